// Round 1
// baseline (220.533 us; speedup 1.0000x reference)
//
#include <hip/hip_runtime.h>
#include <math.h>

#define S_LEN 2048
#define B_SZ 2
#define NH 8
#define DH 64
#define DM 512
#define MROWS 4096  // B*S

typedef __attribute__((ext_vector_type(8))) short s16x8;
typedef __attribute__((ext_vector_type(4))) float fx4;

__device__ inline short f2bf(float x){
  unsigned u = __float_as_uint(x);
  u = (u + 0x7FFFu + ((u >> 16) & 1u)) >> 16;
  return (short)u;
}

__device__ inline fx4 mfma16(s16x8 a, s16x8 b, fx4 c){
  return __builtin_amdgcn_mfma_f32_16x16x32_bf16(a, b, c, 0, 0, 0);
}

// ---- K0: convert f32 weight (K=512 rows, N=512 cols) to bf16 transposed (N,K) ----
__global__ __launch_bounds__(256) void wt_kernel(const float* __restrict__ W,
                                                 short* __restrict__ Wt){
  __shared__ short tile[64][66];
  int n0 = blockIdx.x * 64, k0 = blockIdx.y * 64;
  int t = threadIdx.x;
  int nl = t & 63;
  #pragma unroll
  for (int p = 0; p < 16; ++p){
    int kl = (t >> 6) + p * 4;
    tile[kl][nl] = f2bf(W[(size_t)(k0 + kl) * DM + n0 + nl]);
  }
  __syncthreads();
  int kl2 = t & 63;
  #pragma unroll
  for (int p = 0; p < 16; ++p){
    int nl2 = (t >> 6) + p * 4;
    Wt[(size_t)(n0 + nl2) * DM + k0 + kl2] = tile[kl2][nl2];
  }
}

// ---- K1: Lorentz log map at origin (K=-1): x (B,S,513) f32 -> x_eu (4096,512) bf16 ----
__global__ __launch_bounds__(128) void logmap_kernel(const float* __restrict__ x,
                                                     short* __restrict__ xeu){
  int row = blockIdx.x;
  const float* xr = x + (size_t)row * (DM + 1);
  int t = threadIdx.x;
  float v[4]; float ss = 0.f;
  #pragma unroll
  for (int j = 0; j < 4; ++j){
    v[j] = xr[1 + t + 128 * j];
    ss += v[j] * v[j];
  }
  #pragma unroll
  for (int off = 1; off < 64; off <<= 1) ss += __shfl_xor(ss, off);
  __shared__ float s2[2];
  if ((t & 63) == 0) s2[t >> 6] = ss;
  __syncthreads();
  float tot = s2[0] + s2[1];
  float nrm = sqrtf(tot);
  float xt = xr[0];
  float theta = acoshf(fmaxf(xt, 1.0f + 1e-7f));
  float scl = theta / fmaxf(nrm, 1e-7f);
  #pragma unroll
  for (int j = 0; j < 4; ++j)
    xeu[(size_t)row * DM + t + 128 * j] = f2bf(scl * v[j]);
}

// ---- K2/K5: GEMM  C(4096,512) f32 = A(4096,512) bf16 @ Bt(512 n,512 k)^T bf16 ----
__global__ __launch_bounds__(256) void gemm_kernel(const short* __restrict__ A,
                                                   const short* __restrict__ Bt,
                                                   float* __restrict__ C){
  const int K = DM, N = DM;
  int z = blockIdx.z;
  Bt += (size_t)z * K * N;
  C  += (size_t)z * MROWS * N;
  int n0 = blockIdx.x * 64, m0 = blockIdx.y * 64;
  int w = threadIdx.x >> 6, lane = threadIdx.x & 63;
  int wm = w >> 1, wn = w & 1;
  int lg = lane >> 4, lr = lane & 15;
  const short* Ar = A  + (size_t)(m0 + wm * 32 + lr) * K + 8 * lg;
  const short* Br = Bt + (size_t)(n0 + wn * 32 + lr) * K + 8 * lg;
  fx4 acc[2][2] = {};
  #pragma unroll 4
  for (int kk = 0; kk < K; kk += 32){
    s16x8 a0 = *(const s16x8*)(Ar + kk);
    s16x8 a1 = *(const s16x8*)(Ar + 16 * K + kk);
    s16x8 b0 = *(const s16x8*)(Br + kk);
    s16x8 b1 = *(const s16x8*)(Br + 16 * K + kk);
    acc[0][0] = mfma16(a0, b0, acc[0][0]);
    acc[0][1] = mfma16(a0, b1, acc[0][1]);
    acc[1][0] = mfma16(a1, b0, acc[1][0]);
    acc[1][1] = mfma16(a1, b1, acc[1][1]);
  }
  #pragma unroll
  for (int mi = 0; mi < 2; ++mi)
    #pragma unroll
    for (int ni = 0; ni < 2; ++ni)
      #pragma unroll
      for (int r = 0; r < 4; ++r){
        int row = m0 + wm * 32 + mi * 16 + 4 * lg + r;
        int col = n0 + wn * 32 + ni * 16 + lr;
        C[(size_t)row * N + col] = acc[mi][ni][r];
      }
}

// ---- K3: per-head exp map + score folding ----
// Q,K f32 laid (b,s,h,d) contiguous. Outputs per (b,h): Qt (fold a=c/8), Qs(bf16, fold -a),
// Kt, Ks(bf16) in (B,H,S,·) layout.
__global__ __launch_bounds__(256) void expmap_kernel(const float* __restrict__ Q,
                                                     const float* __restrict__ Kp,
                                                     const float* __restrict__ labsK,
                                                     float* __restrict__ Qt,
                                                     short* __restrict__ Qs,
                                                     float* __restrict__ Kt,
                                                     short* __restrict__ Ks){
  int idx = blockIdx.x * 4 + (threadIdx.x >> 6);   // (b*S+s)*H + h
  int d = threadIdx.x & 63;
  int h = idx & (NH - 1);
  int bs = idx >> 3;
  int s = bs & (S_LEN - 1);
  int b = bs >> 11;
  float c  = __expf(labsK[h]);
  float sc = sqrtf(c);
  float a  = 0.125f * c;
  size_t bhs = ((size_t)(b * NH + h) * S_LEN + s);

  float qv = Q[(size_t)idx * DH + d];
  float ssq = qv * qv;
  #pragma unroll
  for (int off = 1; off < 64; off <<= 1) ssq += __shfl_xor(ssq, off);
  float nq = fmaxf(sqrtf(ssq), 1e-7f);
  float argq = sc * nq;
  if (d == 0) Qt[bhs] = a * coshf(argq) / sc;
  float qscale = -a * sinhf(argq) / argq;
  Qs[bhs * DH + d] = f2bf(qscale * qv);

  float kv = Kp[(size_t)idx * DH + d];
  float ksq = kv * kv;
  #pragma unroll
  for (int off = 1; off < 64; off <<= 1) ksq += __shfl_xor(ksq, off);
  float nk = fmaxf(sqrtf(ksq), 1e-7f);
  float argk = sc * nk;
  if (d == 0) Kt[bhs] = coshf(argk) / sc;
  float kscale = sinhf(argk) / argk;
  Ks[bhs * DH + d] = f2bf(kscale * kv);
}

// ---- K3b: V (b,s,h,d) f32 -> Vt (b,h,d,s) bf16 ----
__global__ __launch_bounds__(256) void vtrans_kernel(const float* __restrict__ V,
                                                     short* __restrict__ Vt){
  __shared__ short tile[64][66];
  int s0 = blockIdx.x * 64;
  int bh = blockIdx.y;
  int b = bh >> 3, h = bh & 7;
  int t = threadIdx.x;
  int dl = t & 63;
  #pragma unroll
  for (int p = 0; p < 16; ++p){
    int sl = (t >> 6) + p * 4;
    tile[sl][dl] = f2bf(V[((size_t)b * S_LEN + s0 + sl) * DM + h * DH + dl]);
  }
  __syncthreads();
  int sl2 = t & 63;
  #pragma unroll
  for (int p = 0; p < 16; ++p){
    int dl2 = (t >> 6) + p * 4;
    Vt[((size_t)bh * DH + dl2) * S_LEN + s0 + sl2] = tile[sl2][dl2];
  }
}

// ---- K4: causal flash attention per (b,h). Block=4 waves, each wave owns 16 queries ----
__global__ __launch_bounds__(256) void attn_kernel(const short* __restrict__ Qs,
                                                   const float* __restrict__ Qt,
                                                   const short* __restrict__ Ks,
                                                   const float* __restrict__ Kt,
                                                   const short* __restrict__ Vt,
                                                   short* __restrict__ Obf){
  int bh = blockIdx.y;
  int w = threadIdx.x >> 6, lane = threadIdx.x & 63;
  int lg = lane >> 4, lr = lane & 15;
  int q0 = blockIdx.x * 64 + w * 16;
  size_t bhS = (size_t)bh * S_LEN;

  // hoisted Q A-fragments (16 q x 64 d)
  s16x8 qa0 = *(const s16x8*)(Qs + (bhS + q0 + lr) * DH + 8 * lg);
  s16x8 qa1 = *(const s16x8*)(Qs + (bhS + q0 + lr) * DH + 32 + 8 * lg);
  float qtf[4];
  #pragma unroll
  for (int r = 0; r < 4; ++r) qtf[r] = Qt[bhS + q0 + 4 * lg + r];

  fx4 acc[4] = {};
  float m[4]    = {-3e38f, -3e38f, -3e38f, -3e38f};
  float lsum[4] = {0.f, 0.f, 0.f, 0.f};

  __shared__ short Pb[4][16][32];
  short (*P)[32] = Pb[w];

  int nkb = (q0 + 47) >> 5;   // key blocks of 32, through the diagonal
  for (int kb = 0; kb < nkb; ++kb){
    int k0 = kb * 32;
    bool needmask = (k0 + 31 > q0);

    fx4 s0t, s1t;
    {
      const short* kr0 = Ks + (bhS + k0 + lr) * DH + 8 * lg;
      const short* kr1 = kr0 + 16 * DH;
      s16x8 b00 = *(const s16x8*)(kr0);
      s16x8 b01 = *(const s16x8*)(kr0 + 32);
      s16x8 b10 = *(const s16x8*)(kr1);
      s16x8 b11 = *(const s16x8*)(kr1 + 32);
      fx4 z = {0.f, 0.f, 0.f, 0.f};
      s0t = mfma16(qa1, b01, mfma16(qa0, b00, z));
      s1t = mfma16(qa1, b11, mfma16(qa0, b10, z));
    }
    float ktv0 = Kt[bhS + k0 + lr];
    float ktv1 = Kt[bhS + k0 + 16 + lr];

    #pragma unroll
    for (int r = 0; r < 4; ++r){
      float s0v = s0t[r] + qtf[r] * ktv0;
      float s1v = s1t[r] + qtf[r] * ktv1;
      if (needmask){
        int qi = q0 + 4 * lg + r;
        if (k0 + lr > qi)      s0v = -3e38f;
        if (k0 + 16 + lr > qi) s1v = -3e38f;
      }
      float tmax = fmaxf(s0v, s1v);
      tmax = fmaxf(tmax, __shfl_xor(tmax, 1));
      tmax = fmaxf(tmax, __shfl_xor(tmax, 2));
      tmax = fmaxf(tmax, __shfl_xor(tmax, 4));
      tmax = fmaxf(tmax, __shfl_xor(tmax, 8));
      float mn = fmaxf(m[r], tmax);
      float scale = __expf(m[r] - mn);
      m[r] = mn;
      float p0 = __expf(s0v - mn);
      float p1 = __expf(s1v - mn);
      float rs = p0 + p1;
      rs += __shfl_xor(rs, 1);
      rs += __shfl_xor(rs, 2);
      rs += __shfl_xor(rs, 4);
      rs += __shfl_xor(rs, 8);
      lsum[r] = lsum[r] * scale + rs;
      acc[0][r] *= scale; acc[1][r] *= scale;
      acc[2][r] *= scale; acc[3][r] *= scale;
      P[4 * lg + r][lr]      = f2bf(p0);
      P[4 * lg + r][16 + lr] = f2bf(p1);
    }

    asm volatile("s_waitcnt lgkmcnt(0)" ::: "memory");
    s16x8 pa = *(const s16x8*)&P[lr][8 * lg];
    #pragma unroll
    for (int nt = 0; nt < 4; ++nt){
      s16x8 vb = *(const s16x8*)(Vt + ((size_t)bh * DH + nt * 16 + lr) * S_LEN + k0 + 8 * lg);
      acc[nt] = mfma16(pa, vb, acc[nt]);
    }
  }

  int b = bh >> 3, h = bh & 7;
  #pragma unroll
  for (int nt = 0; nt < 4; ++nt)
    #pragma unroll
    for (int r = 0; r < 4; ++r){
      float o = acc[nt][r] / lsum[r];
      int q = q0 + 4 * lg + r;
      Obf[((size_t)b * S_LEN + q) * DM + h * DH + nt * 16 + lr] = f2bf(o);
    }
}

extern "C" void kernel_launch(void* const* d_in, const int* in_sizes, int n_in,
                              void* d_out, int out_size, void* d_ws, size_t ws_size,
                              hipStream_t stream) {
  const float* x     = (const float*)d_in[0];
  const float* Wq    = (const float*)d_in[1];
  const float* Wk    = (const float*)d_in[2];
  const float* Wv    = (const float*)d_in[3];
  const float* Wo    = (const float*)d_in[4];
  const float* labsK = (const float*)d_in[5];

  char* w = (char*)d_ws;
  short* Wt  = (short*)(w);                               // 4 x 512x512 bf16 (2 MB)
  short* xeu = (short*)(w + (2ull  << 20));               // 4096x512 bf16 (4 MB)
  float* QKV = (float*)(w + (6ull  << 20));               // 3 x 4096x512 f32 (24 MB)
  short* Qs  = (short*)(w + (30ull << 20));               // 4 MB
  short* Ks  = (short*)(w + (34ull << 20));               // 4 MB
  short* Vt  = (short*)(w + (38ull << 20));               // 4 MB
  float* Qt  = (float*)(w + (42ull << 20));               // 128 KB
  float* Kt  = (float*)(w + (42ull << 20) + (128ull << 10)); // 128 KB
  short* Obf = (short*)(w + (42ull << 20) + (256ull << 10)); // 4 MB

  const int WTE = DM * DM;   // 262144 elements per weight matrix
  wt_kernel<<<dim3(8, 8), 256, 0, stream>>>(Wq, Wt + 0 * WTE);
  wt_kernel<<<dim3(8, 8), 256, 0, stream>>>(Wk, Wt + 1 * WTE);
  wt_kernel<<<dim3(8, 8), 256, 0, stream>>>(Wv, Wt + 2 * WTE);
  wt_kernel<<<dim3(8, 8), 256, 0, stream>>>(Wo, Wt + 3 * WTE);

  logmap_kernel<<<MROWS, 128, 0, stream>>>(x, xeu);

  // Q,K,V projections: z in {0,1,2}
  gemm_kernel<<<dim3(8, 64, 3), 256, 0, stream>>>(xeu, Wt, QKV);

  expmap_kernel<<<(B_SZ * S_LEN * NH) / 4, 256, 0, stream>>>(
      QKV, QKV + (size_t)MROWS * DM, labsK, Qt, Qs, Kt, Ks);

  vtrans_kernel<<<dim3(S_LEN / 64, B_SZ * NH), 256, 0, stream>>>(
      QKV + 2ull * MROWS * DM, Vt);

  attn_kernel<<<dim3(S_LEN / 64, B_SZ * NH), 256, 0, stream>>>(
      Qs, Qt, Ks, Kt, Vt, Obf);

  // output projection
  gemm_kernel<<<dim3(8, 64, 1), 256, 0, stream>>>(Obf, Wt + 3 * WTE, (float*)d_out);
}

// Round 2
// 157.763 us; speedup vs baseline: 1.3979x; 1.3979x over previous
//
#include <hip/hip_runtime.h>
#include <math.h>

#define S_LEN 2048
#define B_SZ 2
#define NH 8
#define DH 64
#define DM 512
#define MROWS 4096  // B*S

typedef __attribute__((ext_vector_type(8))) short s16x8;
typedef __attribute__((ext_vector_type(4))) float fx4;
typedef __attribute__((ext_vector_type(16))) float fx16;
typedef __attribute__((ext_vector_type(4))) int ix4;
typedef __attribute__((ext_vector_type(2))) int ix2;

__device__ inline short f2bf(float x){
  unsigned u = __float_as_uint(x);
  u = (u + 0x7FFFu + ((u >> 16) & 1u)) >> 16;
  return (short)u;
}

__device__ inline fx4 mfma16(s16x8 a, s16x8 b, fx4 c){
  return __builtin_amdgcn_mfma_f32_16x16x32_bf16(a, b, c, 0, 0, 0);
}
__device__ inline fx16 mfma32(s16x8 a, s16x8 b, fx16 c){
  return __builtin_amdgcn_mfma_f32_32x32x16_bf16(a, b, c, 0, 0, 0);
}
__device__ inline int cvtpk(float a, float b){
  int r; asm("v_cvt_pk_bf16_f32 %0, %1, %2" : "=v"(r) : "v"(a), "v"(b)); return r;
}

#define GLL16(g, l) __builtin_amdgcn_global_load_lds((const __attribute__((address_space(1))) void*)(g), (__attribute__((address_space(3))) void*)(l), 16, 0, 0)
#define GLL4(g, l)  __builtin_amdgcn_global_load_lds((const __attribute__((address_space(1))) void*)(g), (__attribute__((address_space(3))) void*)(l), 4, 0, 0)

// ---- K0: convert f32 weight (K=512 rows, N=512 cols) to bf16 transposed (N,K) ----
__global__ __launch_bounds__(256) void wt_kernel(const float* __restrict__ W,
                                                 short* __restrict__ Wt){
  __shared__ short tile[64][66];
  int n0 = blockIdx.x * 64, k0 = blockIdx.y * 64;
  int t = threadIdx.x;
  int nl = t & 63;
  #pragma unroll
  for (int p = 0; p < 16; ++p){
    int kl = (t >> 6) + p * 4;
    tile[kl][nl] = f2bf(W[(size_t)(k0 + kl) * DM + n0 + nl]);
  }
  __syncthreads();
  int kl2 = t & 63;
  #pragma unroll
  for (int p = 0; p < 16; ++p){
    int nl2 = (t >> 6) + p * 4;
    Wt[(size_t)(n0 + nl2) * DM + k0 + kl2] = tile[kl2][nl2];
  }
}

// ---- K1: Lorentz log map at origin (K=-1) ----
__global__ __launch_bounds__(128) void logmap_kernel(const float* __restrict__ x,
                                                     short* __restrict__ xeu){
  int row = blockIdx.x;
  const float* xr = x + (size_t)row * (DM + 1);
  int t = threadIdx.x;
  float v[4]; float ss = 0.f;
  #pragma unroll
  for (int j = 0; j < 4; ++j){
    v[j] = xr[1 + t + 128 * j];
    ss += v[j] * v[j];
  }
  #pragma unroll
  for (int off = 1; off < 64; off <<= 1) ss += __shfl_xor(ss, off);
  __shared__ float s2[2];
  if ((t & 63) == 0) s2[t >> 6] = ss;
  __syncthreads();
  float tot = s2[0] + s2[1];
  float nrm = sqrtf(tot);
  float xt = xr[0];
  float theta = acoshf(fmaxf(xt, 1.0f + 1e-7f));
  float scl = theta / fmaxf(nrm, 1e-7f);
  #pragma unroll
  for (int j = 0; j < 4; ++j)
    xeu[(size_t)row * DM + t + 128 * j] = f2bf(scl * v[j]);
}

// ---- K2/K5: GEMM  C(4096,512) f32 = A(4096,512) bf16 @ Bt(512n,512k)^T bf16 ----
__global__ __launch_bounds__(256) void gemm_kernel(const short* __restrict__ A,
                                                   const short* __restrict__ Bt,
                                                   float* __restrict__ C){
  const int K = DM, N = DM;
  int z = blockIdx.z;
  Bt += (size_t)z * K * N;
  C  += (size_t)z * MROWS * N;
  int n0 = blockIdx.x * 64, m0 = blockIdx.y * 64;
  int w = threadIdx.x >> 6, lane = threadIdx.x & 63;
  int wm = w >> 1, wn = w & 1;
  int lg = lane >> 4, lr = lane & 15;
  const short* Ar = A  + (size_t)(m0 + wm * 32 + lr) * K + 8 * lg;
  const short* Br = Bt + (size_t)(n0 + wn * 32 + lr) * K + 8 * lg;
  fx4 acc[2][2] = {};
  #pragma unroll 4
  for (int kk = 0; kk < K; kk += 32){
    s16x8 a0 = *(const s16x8*)(Ar + kk);
    s16x8 a1 = *(const s16x8*)(Ar + 16 * K + kk);
    s16x8 b0 = *(const s16x8*)(Br + kk);
    s16x8 b1 = *(const s16x8*)(Br + 16 * K + kk);
    acc[0][0] = mfma16(a0, b0, acc[0][0]);
    acc[0][1] = mfma16(a0, b1, acc[0][1]);
    acc[1][0] = mfma16(a1, b0, acc[1][0]);
    acc[1][1] = mfma16(a1, b1, acc[1][1]);
  }
  #pragma unroll
  for (int mi = 0; mi < 2; ++mi)
    #pragma unroll
    for (int ni = 0; ni < 2; ++ni)
      #pragma unroll
      for (int r = 0; r < 4; ++r){
        int row = m0 + wm * 32 + mi * 16 + 4 * lg + r;
        int col = n0 + wn * 32 + ni * 16 + lr;
        C[(size_t)row * N + col] = acc[mi][ni][r];
      }
}

// ---- K3: per-head exp map + score folding (log2e folded into a) ----
__global__ __launch_bounds__(256) void expmap_kernel(const float* __restrict__ Q,
                                                     const float* __restrict__ Kp,
                                                     const float* __restrict__ labsK,
                                                     float* __restrict__ Qt,
                                                     short* __restrict__ Qs,
                                                     float* __restrict__ Kt,
                                                     short* __restrict__ Ks){
  int idx = blockIdx.x * 4 + (threadIdx.x >> 6);   // (b*S+s)*H + h
  int d = threadIdx.x & 63;
  int h = idx & (NH - 1);
  int bs = idx >> 3;
  int s = bs & (S_LEN - 1);
  int b = bs >> 11;
  float c  = __expf(labsK[h]);
  float sc = sqrtf(c);
  float a  = 0.125f * c * 1.4426950408889634f;   // fold log2(e): softmax uses exp2
  size_t bhs = ((size_t)(b * NH + h) * S_LEN + s);

  float qv = Q[(size_t)idx * DH + d];
  float ssq = qv * qv;
  #pragma unroll
  for (int off = 1; off < 64; off <<= 1) ssq += __shfl_xor(ssq, off);
  float nq = fmaxf(sqrtf(ssq), 1e-7f);
  float argq = sc * nq;
  if (d == 0) Qt[bhs] = a * coshf(argq) / sc;
  float qscale = -a * sinhf(argq) / argq;
  Qs[bhs * DH + d] = f2bf(qscale * qv);

  float kv = Kp[(size_t)idx * DH + d];
  float ksq = kv * kv;
  #pragma unroll
  for (int off = 1; off < 64; off <<= 1) ksq += __shfl_xor(ksq, off);
  float nk = fmaxf(sqrtf(ksq), 1e-7f);
  float argk = sc * nk;
  if (d == 0) Kt[bhs] = coshf(argk) / sc;
  float kscale = sinhf(argk) / argk;
  Ks[bhs * DH + d] = f2bf(kscale * kv);
}

// ---- K3b: V (b,s,h,d) f32 -> Vt (b,h,d,s) bf16 ----
__global__ __launch_bounds__(256) void vtrans_kernel(const float* __restrict__ V,
                                                     short* __restrict__ Vt){
  __shared__ short tile[64][66];
  int s0 = blockIdx.x * 64;
  int bh = blockIdx.y;
  int b = bh >> 3, h = bh & 7;
  int t = threadIdx.x;
  int dl = t & 63;
  #pragma unroll
  for (int p = 0; p < 16; ++p){
    int sl = (t >> 6) + p * 4;
    tile[sl][dl] = f2bf(V[((size_t)b * S_LEN + s0 + sl) * DM + h * DH + dl]);
  }
  __syncthreads();
  int sl2 = t & 63;
  #pragma unroll
  for (int p = 0; p < 16; ++p){
    int dl2 = (t >> 6) + p * 4;
    Vt[((size_t)bh * DH + dl2) * S_LEN + s0 + sl2] = tile[sl2][dl2];
  }
}

// ---- K4: flash attention, 4 waves x 32q = 128-q block, KV tiles of 64 LDS-staged,
//      swapped QK^T (32x32x16), in-lane softmax, in-register P handoff ----
__global__ __launch_bounds__(256) void attn_kernel(const short* __restrict__ Qs,
                                                   const float* __restrict__ Qt,
                                                   const short* __restrict__ Ks,
                                                   const float* __restrict__ Kt,
                                                   const short* __restrict__ Vt,
                                                   short* __restrict__ Obf){
  __shared__ __attribute__((aligned(16))) short Ksm[2][4096];
  __shared__ __attribute__((aligned(16))) short Vsm[2][4096];
  __shared__ __attribute__((aligned(16))) float Ktm[2][64];

  int bx = blockIdx.x;
  int bh = bx & 15;                 // XCD-local heads: xcd = bx%8 -> bh%8 fixed per XCD
  int jblk = 15 - (bx >> 4);        // longest diagonal blocks dispatched first
  int qB = jblk * 128;
  int tid = threadIdx.x;
  int w = tid >> 6, lane = tid & 63;
  int l5 = lane & 31, hi = lane >> 5;
  size_t bhS = (size_t)bh * S_LEN;

  const short* Kg  = Ks + bhS * DH;
  const short* Vg  = Vt + (size_t)bh * DH * S_LEN;
  const float* Ktg = Kt + bhS;

  // staging source addresses (XOR-swizzled on the global side; LDS dest linear)
  int srow = lane >> 3;                                // 0..7
  int scol = ((lane & 7) * 8) ^ (srow << 3);           // elements, 16B granules
  const short* kg0 = Kg + (size_t)(16 * w + srow) * DH + scol;
  const short* kg1 = kg0 + 8 * DH;
  const short* vg0 = Vg + (size_t)(16 * w + srow) * S_LEN + scol;
  const short* vg1 = vg0 + 8 * S_LEN;
  const float* ktg = Ktg + lane;
  short* Kd0 = &Ksm[0][16 * w * 64]; short* Kd1 = Kd0 + 512;
  short* Vd0 = &Vsm[0][16 * w * 64]; short* Vd1 = Vd0 + 512;

  // hoist Q fragments (B operand: col=q=lane&31, k(d)=8*hi+j)
  int q0w = qB + 32 * w;
  int q   = q0w + l5;
  int qmax = q0w + 31;
  s16x8 qf[4];
  #pragma unroll
  for (int dblk = 0; dblk < 4; ++dblk)
    qf[dblk] = *(const s16x8*)(Qs + (bhS + q) * DH + dblk * 16 + hi * 8);
  float aqt = Qt[bhS + q];

  fx16 acc0, acc1;
  #pragma unroll
  for (int i = 0; i < 16; ++i){ acc0[i] = 0.f; acc1[i] = 0.f; }
  float mrun = 0.f, lrun = 0.f;   // m init 0 (any finite m is valid; keeps masked p at 0)

  int nt = (qB >> 6) + 2;

  // prologue: stage tile 0 into buf 0
  {
    GLL16(kg0, Kd0); GLL16(kg1, Kd1);
    GLL16(vg0, Vd0); GLL16(vg1, Vd1);
    if (w == 3) GLL4(ktg, &Ktm[0][0]);
  }
  int buf = 0;

  for (int t = 0; t < nt; ++t){
    int k0 = t * 64;
    if (t + 1 < nt){
      int k0n = k0 + 64;
      int bn = buf ^ 1;
      GLL16(kg0 + (size_t)k0n * DH, &Ksm[bn][16 * w * 64]);
      GLL16(kg1 + (size_t)k0n * DH, &Ksm[bn][16 * w * 64 + 512]);
      GLL16(vg0 + k0n, &Vsm[bn][16 * w * 64]);
      GLL16(vg1 + k0n, &Vsm[bn][16 * w * 64 + 512]);
      if (w == 3){
        GLL4(ktg + k0n, &Ktm[bn][0]);
        asm volatile("s_waitcnt vmcnt(5)" ::: "memory");
      } else {
        asm volatile("s_waitcnt vmcnt(4)" ::: "memory");
      }
    } else {
      asm volatile("s_waitcnt vmcnt(0)" ::: "memory");
    }
    __builtin_amdgcn_s_barrier();

    if (k0 <= qmax){
      // ---- QK^T (swapped): S^T(k,q) ----
      fx16 st[2];
      #pragma unroll
      for (int s = 0; s < 2; ++s){
        const short* kb = &Ksm[buf][(32 * s + l5) * 64];
        fx16 z;
        #pragma unroll
        for (int i = 0; i < 16; ++i) z[i] = 0.f;
        #pragma unroll
        for (int dblk = 0; dblk < 4; ++dblk){
          s16x8 kf = *(const s16x8*)(kb + ((16 * dblk + 8 * hi) ^ ((l5 & 7) << 3)));
          z = mfma32(kf, qf[dblk], z);
        }
        st[s] = z;
      }
      // ---- rank-1 Lorentz time term + causal mask ----
      float p[2][16];
      #pragma unroll
      for (int s = 0; s < 2; ++s)
        #pragma unroll
        for (int m4 = 0; m4 < 4; ++m4){
          fx4 kt4 = *(const fx4*)&Ktm[buf][32 * s + 8 * m4 + 4 * hi];
          #pragma unroll
          for (int tt = 0; tt < 4; ++tt)
            p[s][4 * m4 + tt] = st[s][4 * m4 + tt] + aqt * kt4[tt];
        }
      if (k0 + 63 > q0w){
        #pragma unroll
        for (int s = 0; s < 2; ++s)
          #pragma unroll
          for (int r = 0; r < 16; ++r){
            int kg2 = k0 + 32 * s + (r & 3) + 8 * (r >> 2) + 4 * hi;
            if (kg2 > q) p[s][r] = -3e38f;
          }
      }
      // ---- online softmax: full row is in-lane (32) + partner lane (32) ----
      float tmax = p[0][0];
      #pragma unroll
      for (int s = 0; s < 2; ++s)
        #pragma unroll
        for (int r = 0; r < 16; ++r) tmax = fmaxf(tmax, p[s][r]);
      tmax = fmaxf(tmax, __shfl_xor(tmax, 32));
      float mnew = fmaxf(mrun, tmax);
      float scl = __builtin_amdgcn_exp2f(mrun - mnew);
      mrun = mnew;
      float rsum = 0.f;
      #pragma unroll
      for (int s = 0; s < 2; ++s)
        #pragma unroll
        for (int r = 0; r < 16; ++r){
          p[s][r] = __builtin_amdgcn_exp2f(p[s][r] - mnew);
          rsum += p[s][r];
        }
      rsum += __shfl_xor(rsum, 32);
      lrun = lrun * scl + rsum;
      #pragma unroll
      for (int i = 0; i < 16; ++i){ acc0[i] *= scl; acc1[i] *= scl; }

      // ---- pack P to bf16 B-fragments + PV (O^T accumulation) ----
      #pragma unroll
      for (int h = 0; h < 4; ++h){
        int s = h >> 1, hb = h & 1;
        int w0 = cvtpk(p[s][8 * hb + 0], p[s][8 * hb + 1]);
        int w1 = cvtpk(p[s][8 * hb + 2], p[s][8 * hb + 3]);
        int w2 = cvtpk(p[s][8 * hb + 4], p[s][8 * hb + 5]);
        int w3 = cvtpk(p[s][8 * hb + 6], p[s][8 * hb + 7]);
        int sdA = hi ? w0 : w2;
        int sdB = hi ? w1 : w3;
        int rcA = __shfl_xor(sdA, 32);
        int rcB = __shfl_xor(sdB, 32);
        ix4 fw;
        fw.x = hi ? rcA : w0; fw.y = hi ? rcB : w1;
        fw.z = hi ? w2 : rcA; fw.w = hi ? w3 : rcB;
        s16x8 pf = __builtin_bit_cast(s16x8, fw);
        const short* vb0 = &Vsm[buf][(l5) * 64 + ((16 * h + 8 * hi) ^ ((l5 & 7) << 3))];
        const short* vb1 = vb0 + 32 * 64;
        s16x8 vf0 = *(const s16x8*)vb0;
        s16x8 vf1 = *(const s16x8*)vb1;
        acc0 = mfma32(vf0, pf, acc0);
        acc1 = mfma32(vf1, pf, acc1);
      }
    }
    __builtin_amdgcn_s_barrier();
    buf ^= 1;
  }

  // ---- epilogue: O = acc/lsum, LDS transpose (per-wave region), coalesced store ----
  __syncthreads();
  short* sw = ((short*)Ksm) + w * 2048;   // 4KB per wave
  float inv = 1.0f / lrun;
  #pragma unroll
  for (int dblk = 0; dblk < 2; ++dblk)
    #pragma unroll
    for (int m4 = 0; m4 < 4; ++m4){
      float o0 = (dblk ? acc1[4 * m4 + 0] : acc0[4 * m4 + 0]) * inv;
      float o1 = (dblk ? acc1[4 * m4 + 1] : acc0[4 * m4 + 1]) * inv;
      float o2 = (dblk ? acc1[4 * m4 + 2] : acc0[4 * m4 + 2]) * inv;
      float o3 = (dblk ? acc1[4 * m4 + 3] : acc0[4 * m4 + 3]) * inv;
      int a01 = cvtpk(o0, o1), a23 = cvtpk(o2, o3);
      int boff = (16 * m4 + 8 * hi + 64 * dblk) ^ ((l5 & 7) << 4);
      ix2 val; val.x = a01; val.y = a23;
      *(ix2*)(sw + l5 * 64 + (boff >> 1)) = val;
    }
  asm volatile("s_waitcnt lgkmcnt(0)" ::: "memory");
  __builtin_amdgcn_sched_barrier(0);
  int bb = bh >> 3, hh = bh & 7;
  #pragma unroll
  for (int i = 0; i < 4; ++i){
    int qr = 8 * i + (lane >> 3);
    s16x8 ov = *(const s16x8*)(sw + qr * 64 + ((((lane & 7) * 16) ^ ((lane >> 3) << 4)) >> 1));
    *(s16x8*)(Obf + ((size_t)bb * S_LEN + qB + 32 * w + qr) * DM + hh * DH + (lane & 7) * 8) = ov;
  }
}

extern "C" void kernel_launch(void* const* d_in, const int* in_sizes, int n_in,
                              void* d_out, int out_size, void* d_ws, size_t ws_size,
                              hipStream_t stream) {
  const float* x     = (const float*)d_in[0];
  const float* Wq    = (const float*)d_in[1];
  const float* Wk    = (const float*)d_in[2];
  const float* Wv    = (const float*)d_in[3];
  const float* Wo    = (const float*)d_in[4];
  const float* labsK = (const float*)d_in[5];

  char* w = (char*)d_ws;
  short* Wt  = (short*)(w);                               // 4 x 512x512 bf16 (2 MB)
  short* xeu = (short*)(w + (2ull  << 20));               // 4096x512 bf16 (4 MB)
  float* QKV = (float*)(w + (6ull  << 20));               // 3 x 4096x512 f32 (24 MB)
  short* Qs  = (short*)(w + (30ull << 20));               // 4 MB
  short* Ks  = (short*)(w + (34ull << 20));               // 4 MB
  short* Vt  = (short*)(w + (38ull << 20));               // 4 MB
  float* Qt  = (float*)(w + (42ull << 20));               // 128 KB
  float* Kt  = (float*)(w + (42ull << 20) + (128ull << 10)); // 128 KB
  short* Obf = (short*)(w + (42ull << 20) + (256ull << 10)); // 4 MB

  const int WTE = DM * DM;
  wt_kernel<<<dim3(8, 8), 256, 0, stream>>>(Wq, Wt + 0 * WTE);
  wt_kernel<<<dim3(8, 8), 256, 0, stream>>>(Wk, Wt + 1 * WTE);
  wt_kernel<<<dim3(8, 8), 256, 0, stream>>>(Wv, Wt + 2 * WTE);
  wt_kernel<<<dim3(8, 8), 256, 0, stream>>>(Wo, Wt + 3 * WTE);

  logmap_kernel<<<MROWS, 128, 0, stream>>>(x, xeu);

  gemm_kernel<<<dim3(8, 64, 3), 256, 0, stream>>>(xeu, Wt, QKV);

  expmap_kernel<<<(B_SZ * S_LEN * NH) / 4, 256, 0, stream>>>(
      QKV, QKV + (size_t)MROWS * DM, labsK, Qt, Qs, Kt, Ks);

  vtrans_kernel<<<dim3(S_LEN / 64, B_SZ * NH), 256, 0, stream>>>(
      QKV + 2ull * MROWS * DM, Vt);

  attn_kernel<<<dim3(256), 256, 0, stream>>>(Qs, Qt, Ks, Kt, Vt, Obf);

  gemm_kernel<<<dim3(8, 64, 1), 256, 0, stream>>>(Obf, Wt + 3 * WTE, (float*)d_out);
}